// Round 1
// baseline (620.538 us; speedup 1.0000x reference)
//
#include <hip/hip_runtime.h>
#include <stdint.h>

#define B_ 8
#define N_ 8192
#define DIM_ 512
#define H_ 8
#define DH_ 64
#define ROWS (B_*N_)        // 65536
#define TRIPLE (3*DIM_)     // 1536
#define EPS_ 1e-5f

typedef __attribute__((ext_vector_type(8))) short short8;
typedef __attribute__((ext_vector_type(4))) float f32x4;
typedef __attribute__((ext_vector_type(4))) float fl4;
typedef __attribute__((ext_vector_type(4))) unsigned short us4;

__device__ inline unsigned short f2bf(float f) {
    union { float f; unsigned int u; } x; x.f = f;
    unsigned int r = x.u + 0x7fffu + ((x.u >> 16) & 1u);
    return (unsigned short)(r >> 16);
}
__device__ inline float bf2f(unsigned short b) {
    union { unsigned int u; float f; } x; x.u = ((unsigned int)b) << 16;
    return x.f;
}

// ---------------------------------------------------------------------------
// k_prep: transpose+convert weights to bf16 [n][k] so MFMA B-fragments read
// contiguous k via ds_read_b128.
__global__ void k_prep(const float* __restrict__ w_qkv, const float* __restrict__ w_out,
                       unsigned short* __restrict__ wqkvT, unsigned short* __restrict__ woutT) {
    int idx = blockIdx.x * 256 + threadIdx.x;
    if (idx < TRIPLE * DIM_) {
        int n = idx / DIM_, k = idx - n * DIM_;
        wqkvT[idx] = f2bf(w_qkv[(size_t)k * TRIPLE + n]);
    }
    if (idx < DIM_ * DIM_) {
        int n = idx / DIM_, k = idx - n * DIM_;
        woutT[idx] = f2bf(w_out[(size_t)k * DIM_ + n]);
    }
}

// ---------------------------------------------------------------------------
// k_qkv: C[65536x1536] = x[65536x512] @ w_qkv, bf16 MFMA, relu on cols<1024,
// writes bf16 QKV. 128x128 tile, BK=32, 256 threads (4 waves, 4x4 frags each).
__global__ __launch_bounds__(256) void k_qkv(const float* __restrict__ x,
        const unsigned short* __restrict__ wT,      // [1536][512] bf16
        unsigned short* __restrict__ qkv)           // [65536][1536] bf16
{
    __shared__ unsigned short As[128][40];
    __shared__ unsigned short Bs[128][40];
    int t = threadIdx.x;
    int lane = t & 63, wave = t >> 6;
    int m0 = blockIdx.y * 128;
    int n0 = blockIdx.x * 128;
    int wm = (wave & 1) * 64, wn = (wave >> 1) * 64;
    int lr = lane & 15, kg = (lane >> 4) * 8;

    f32x4 acc[4][4] = {};
    for (int k0 = 0; k0 < DIM_; k0 += 32) {
        // stage A: x tile [128][32] fp32 -> bf16
#pragma unroll
        for (int i = 0; i < 4; ++i) {
            int c = t + 256 * i;               // 1024 float4 chunks
            int r = c >> 3, c4 = (c & 7) * 4;
            fl4 v = *(const fl4*)(x + (size_t)(m0 + r) * DIM_ + k0 + c4);
            unsigned short* dst = &As[r][c4];
            dst[0] = f2bf(v[0]); dst[1] = f2bf(v[1]); dst[2] = f2bf(v[2]); dst[3] = f2bf(v[3]);
        }
        // stage B: wT tile [128][32] bf16, 16B chunks
#pragma unroll
        for (int i = 0; i < 2; ++i) {
            int c = t + 256 * i;               // 512 x 16B chunks
            int r = c >> 2, c8 = (c & 3) * 8;
            *(int4*)&Bs[r][c8] = *(const int4*)(wT + (size_t)(n0 + r) * DIM_ + k0 + c8);
        }
        __syncthreads();
        short8 af[4], bfr[4];
#pragma unroll
        for (int i = 0; i < 4; ++i) af[i]  = *(short8*)&As[wm + i*16 + lr][kg];
#pragma unroll
        for (int j = 0; j < 4; ++j) bfr[j] = *(short8*)&Bs[wn + j*16 + lr][kg];
#pragma unroll
        for (int i = 0; i < 4; ++i)
#pragma unroll
            for (int j = 0; j < 4; ++j)
                acc[i][j] = __builtin_amdgcn_mfma_f32_16x16x32_bf16(af[i], bfr[j], acc[i][j], 0, 0, 0);
        __syncthreads();
    }
    // epilogue: relu for q,k columns (global col < 1024), convert bf16, store
#pragma unroll
    for (int i = 0; i < 4; ++i) {
        int row = m0 + wm + i*16 + (lane >> 4) * 4;
#pragma unroll
        for (int j = 0; j < 4; ++j) {
            int col = n0 + wn + j*16 + (lane & 15);
            bool rl = (col < 1024);
#pragma unroll
            for (int r = 0; r < 4; ++r) {
                float v = acc[i][j][r];
                if (rl && v < 0.0f) v = 0.0f;
                qkv[(size_t)(row + r) * TRIPLE + col] = f2bf(v);
            }
        }
    }
}

// ---------------------------------------------------------------------------
// k_kv: kv[b,h] (64x64) = sum_n relu(k)[n][m] * v[n][d].  MFMA with A=K^T,
// B^T=V^T staged via LDS transpose.  Grid (64 bh, 8 chunks); split-K atomics.
__global__ __launch_bounds__(256) void k_kv(const unsigned short* __restrict__ qkv,
                                            float* __restrict__ kv) // [64][64][64] fp32
{
    __shared__ unsigned short KT[64][136];
    __shared__ unsigned short VT[64][136];
    __shared__ float red[64 * 64];
    int t = threadIdx.x, lane = t & 63, wave = t >> 6;
    int bh = blockIdx.x;            // 0..63
    int b = bh >> 3, h = bh & 7;
    int chunk = blockIdx.y;         // 0..7
    size_t rowbase = (size_t)b * N_ + (size_t)chunk * 1024;
    int kcol = DIM_ + h * 64;
    int vcol = 2 * DIM_ + h * 64;
    int lr = lane & 15;

    f32x4 acc[4][4] = {};
    for (int tile = 0; tile < 8; ++tile) {
        size_t r0 = rowbase + tile * 128;
        // stage K,V tiles transposed: LDS[feat][n]
#pragma unroll
        for (int i = 0; i < 8; ++i) {
            int c = t + 256 * i;            // 2048 ushort4 chunks
            int r = c >> 4, f4 = (c & 15) * 4;
            us4 kq = *(const us4*)(qkv + (r0 + r) * TRIPLE + kcol + f4);
            us4 vq = *(const us4*)(qkv + (r0 + r) * TRIPLE + vcol + f4);
#pragma unroll
            for (int j = 0; j < 4; ++j) { KT[f4 + j][r] = kq[j]; VT[f4 + j][r] = vq[j]; }
        }
        __syncthreads();
        int kg = wave * 32 + (lane >> 4) * 8;   // each wave takes its own 32-row slice
        short8 af[4], bfr[4];
#pragma unroll
        for (int i = 0; i < 4; ++i) af[i]  = *(short8*)&KT[i*16 + lr][kg];
#pragma unroll
        for (int j = 0; j < 4; ++j) bfr[j] = *(short8*)&VT[j*16 + lr][kg];
#pragma unroll
        for (int i = 0; i < 4; ++i)
#pragma unroll
            for (int j = 0; j < 4; ++j)
                acc[i][j] = __builtin_amdgcn_mfma_f32_16x16x32_bf16(af[i], bfr[j], acc[i][j], 0, 0, 0);
        __syncthreads();
    }
    // reduce 4 waves' accumulators in LDS
    for (int w = 0; w < 4; ++w) {
        if (wave == w) {
#pragma unroll
            for (int i = 0; i < 4; ++i)
#pragma unroll
                for (int j = 0; j < 4; ++j)
#pragma unroll
                    for (int r = 0; r < 4; ++r) {
                        int m = i*16 + (lane >> 4) * 4 + r;
                        int d = j*16 + (lane & 15);
                        if (w == 0) red[m * 64 + d] = acc[i][j][r];
                        else        red[m * 64 + d] += acc[i][j][r];
                    }
        }
        __syncthreads();
    }
    float* kvout = kv + (size_t)bh * 4096;
#pragma unroll
    for (int i = 0; i < 16; ++i) {
        int idx = t + 256 * i;
        atomicAdd(&kvout[idx], red[idx]);
    }
}

// ---------------------------------------------------------------------------
// k_attn: attn = relu(q) @ kv per head (K=64), bf16 result written IN PLACE
// over the Q columns (head h reads/writes only cols h*64..h*64+63; Q is staged
// to LDS before the overwrite).  128-row tiles.
__global__ __launch_bounds__(256) void k_attn(unsigned short* __restrict__ qkv,
                                              const float* __restrict__ kv)
{
    __shared__ unsigned short Qh[128][72];
    __shared__ unsigned short kvT[64][72];
    int t = threadIdx.x, lane = t & 63, wave = t >> 6;
    size_t r0 = (size_t)blockIdx.x * 128;
    int b = (int)(r0 / N_);          // tiles never cross batch boundary (8192%128==0)
    int lr = lane & 15;
    for (int h = 0; h < H_; ++h) {
        // stage Q_h [128][64]
#pragma unroll
        for (int i = 0; i < 8; ++i) {
            int c = t + 256 * i;     // 2048 ushort4 chunks
            int r = c >> 4, f4 = (c & 15) * 4;
            *(us4*)&Qh[r][f4] = *(const us4*)(qkv + (r0 + r) * TRIPLE + h * 64 + f4);
        }
        // stage kv_h transposed to bf16: kvT[d][m]
        const float* kvh = kv + (size_t)(b * 8 + h) * 4096;
#pragma unroll
        for (int i = 0; i < 16; ++i) {
            int idx = t + 256 * i;
            int m = idx >> 6, d = idx & 63;
            kvT[d][m] = f2bf(kvh[idx]);
        }
        __syncthreads();
        // wave handles rows wave*32 .. +32
        f32x4 acc[2][4] = {};
#pragma unroll
        for (int ks = 0; ks < 2; ++ks) {
            int kg = ks * 32 + (lane >> 4) * 8;
            short8 af[2], bfr[4];
#pragma unroll
            for (int i = 0; i < 2; ++i) af[i]  = *(short8*)&Qh[wave*32 + i*16 + lr][kg];
#pragma unroll
            for (int j = 0; j < 4; ++j) bfr[j] = *(short8*)&kvT[j*16 + lr][kg];
#pragma unroll
            for (int i = 0; i < 2; ++i)
#pragma unroll
                for (int j = 0; j < 4; ++j)
                    acc[i][j] = __builtin_amdgcn_mfma_f32_16x16x32_bf16(af[i], bfr[j], acc[i][j], 0, 0, 0);
        }
        __syncthreads();   // all LDS reads done before next head restages
        // write attn (bf16) over the Q columns of this head
#pragma unroll
        for (int i = 0; i < 2; ++i)
#pragma unroll
            for (int j = 0; j < 4; ++j) {
                int row = wave*32 + i*16 + (lane >> 4) * 4;
                int col = h*64 + j*16 + (lane & 15);
#pragma unroll
                for (int r = 0; r < 4; ++r)
                    qkv[(r0 + row + r) * TRIPLE + col] = f2bf(acc[i][j][r]);
            }
    }
}

// ---------------------------------------------------------------------------
// k_out: LayerNorm(attn) @ w_out + b_out -> fp32 out.  Stats pre-pass, then
// 128x128 MFMA GEMM with normalization fused into A-staging.
__global__ __launch_bounds__(256) void k_out(const unsigned short* __restrict__ qkv,
        const unsigned short* __restrict__ woutT,   // [512][512] bf16 (w_out^T)
        const float* __restrict__ lnw, const float* __restrict__ lnb,
        const float* __restrict__ bout, float* __restrict__ out)
{
    __shared__ unsigned short As[128][40];
    __shared__ unsigned short Bs[128][40];
    __shared__ float mu[128], rs[128], lw[512], lb[512];
    int t = threadIdx.x, lane = t & 63, wave = t >> 6;
    int m0 = blockIdx.y * 128, n0 = blockIdx.x * 128;
    int wm = (wave & 1) * 64, wn = (wave >> 1) * 64;
    int lr = lane & 15, kg = (lane >> 4) * 8;

    for (int i = t; i < 512; i += 256) { lw[i] = lnw[i]; lb[i] = lnb[i]; }
    // stats: 2 threads per row, 256 bf16 values each
    {
        int row = t >> 1, half = t & 1;
        const unsigned short* p = qkv + (size_t)(m0 + row) * TRIPLE + half * 256;
        float s = 0.0f, ss = 0.0f;
#pragma unroll 8
        for (int i = 0; i < 64; ++i) {
            us4 v = *(const us4*)(p + i * 4);
#pragma unroll
            for (int j = 0; j < 4; ++j) { float f = bf2f(v[j]); s += f; ss += f * f; }
        }
        s  += __shfl_xor(s, 1);
        ss += __shfl_xor(ss, 1);
        if (half == 0) {
            float m = s * (1.0f / 512.0f);
            float var = ss * (1.0f / 512.0f) - m * m;
            mu[row] = m;
            rs[row] = rsqrtf(var + EPS_);
        }
    }
    __syncthreads();

    f32x4 acc[4][4] = {};
    for (int k0 = 0; k0 < 512; k0 += 32) {
        // stage A: normalized attn -> bf16
#pragma unroll
        for (int i = 0; i < 4; ++i) {
            int c = t + 256 * i;            // 1024 ushort4 chunks
            int r = c >> 3, c4 = (c & 7) * 4;
            us4 v = *(const us4*)(qkv + (size_t)(m0 + r) * TRIPLE + k0 + c4);
            float mm = mu[r], rr = rs[r];
            unsigned short* dst = &As[r][c4];
#pragma unroll
            for (int j = 0; j < 4; ++j) {
                float f = (bf2f(v[j]) - mm) * rr * lw[k0 + c4 + j] + lb[k0 + c4 + j];
                dst[j] = f2bf(f);
            }
        }
        // stage B: woutT tile
#pragma unroll
        for (int i = 0; i < 2; ++i) {
            int c = t + 256 * i;
            int r = c >> 2, c8 = (c & 3) * 8;
            *(int4*)&Bs[r][c8] = *(const int4*)(woutT + (size_t)(n0 + r) * DIM_ + k0 + c8);
        }
        __syncthreads();
        short8 af[4], bfr[4];
#pragma unroll
        for (int i = 0; i < 4; ++i) af[i]  = *(short8*)&As[wm + i*16 + lr][kg];
#pragma unroll
        for (int j = 0; j < 4; ++j) bfr[j] = *(short8*)&Bs[wn + j*16 + lr][kg];
#pragma unroll
        for (int i = 0; i < 4; ++i)
#pragma unroll
            for (int j = 0; j < 4; ++j)
                acc[i][j] = __builtin_amdgcn_mfma_f32_16x16x32_bf16(af[i], bfr[j], acc[i][j], 0, 0, 0);
        __syncthreads();
    }
#pragma unroll
    for (int i = 0; i < 4; ++i) {
        int row = m0 + wm + i*16 + (lane >> 4) * 4;
#pragma unroll
        for (int j = 0; j < 4; ++j) {
            int col = n0 + wn + j*16 + (lane & 15);
            float bo = bout[col];
#pragma unroll
            for (int r = 0; r < 4; ++r)
                out[(size_t)(row + r) * DIM_ + col] = acc[i][j][r] + bo;
        }
    }
}

// ---------------------------------------------------------------------------
extern "C" void kernel_launch(void* const* d_in, const int* in_sizes, int n_in,
                              void* d_out, int out_size, void* d_ws, size_t ws_size,
                              hipStream_t stream) {
    (void)in_sizes; (void)n_in; (void)out_size; (void)ws_size;
    const float* x     = (const float*)d_in[0];
    const float* w_qkv = (const float*)d_in[1];
    const float* ln_w  = (const float*)d_in[2];
    const float* ln_b  = (const float*)d_in[3];
    const float* w_out = (const float*)d_in[4];
    const float* b_out = (const float*)d_in[5];
    float* out = (float*)d_out;

    char* ws = (char*)d_ws;
    const size_t QKV_BYTES  = (size_t)ROWS * TRIPLE * sizeof(unsigned short); // 201326592
    const size_t KV_BYTES   = (size_t)64 * 64 * 64 * sizeof(float);           // 1048576
    const size_t WQT_BYTES  = (size_t)TRIPLE * DIM_ * sizeof(unsigned short); // 1572864
    unsigned short* qkv   = (unsigned short*)ws;
    float*          kvbuf = (float*)(ws + QKV_BYTES);
    unsigned short* wqkvT = (unsigned short*)(ws + QKV_BYTES + KV_BYTES);
    unsigned short* woutT = (unsigned short*)(ws + QKV_BYTES + KV_BYTES + WQT_BYTES);

    hipMemsetAsync(kvbuf, 0, KV_BYTES, stream);
    k_prep<<<3072, 256, 0, stream>>>(w_qkv, w_out, wqkvT, woutT);
    k_qkv<<<dim3(12, 512), 256, 0, stream>>>(x, wqkvT, qkv);
    k_kv<<<dim3(64, 8), 256, 0, stream>>>(qkv, kvbuf);
    k_attn<<<512, 256, 0, stream>>>(qkv, kvbuf);
    k_out<<<dim3(4, 512), 256, 0, stream>>>(qkv, woutT, ln_w, ln_b, b_out, out);
}

// Round 2
// 575.411 us; speedup vs baseline: 1.0784x; 1.0784x over previous
//
#include <hip/hip_runtime.h>
#include <stdint.h>

#define B_ 8
#define N_ 8192
#define DIM_ 512
#define H_ 8
#define DH_ 64
#define ROWS (B_*N_)        // 65536
#define TRIPLE (3*DIM_)     // 1536
#define EPS_ 1e-5f

typedef __attribute__((ext_vector_type(8))) short short8;
typedef __attribute__((ext_vector_type(4))) float f32x4;
typedef __attribute__((ext_vector_type(4))) float fl4;
typedef __attribute__((ext_vector_type(4))) unsigned short us4;
typedef __attribute__((ext_vector_type(8))) unsigned short us8;

#define AS1 __attribute__((address_space(1)))
#define AS3 __attribute__((address_space(3)))

__device__ __forceinline__ void gld16(const void* g, void* l) {
    // async global->LDS, 16B/lane; LDS dest = wave-uniform base + lane*16
    __builtin_amdgcn_global_load_lds((const AS1 void*)(uintptr_t)g,
                                     (AS3 void*)(unsigned)(uintptr_t)l, 16, 0, 0);
}

__device__ inline unsigned short f2bf(float f) {
    union { float f; unsigned int u; } x; x.f = f;
    unsigned int r = x.u + 0x7fffu + ((x.u >> 16) & 1u);
    return (unsigned short)(r >> 16);
}
__device__ inline float bf2f(unsigned short b) {
    union { unsigned int u; float f; } x; x.u = ((unsigned int)b) << 16;
    return x.f;
}

// ---------------------------------------------------------------------------
// k_cvt: x fp32 -> bf16 (row-major unchanged), enables async A-staging in k_qkv
__global__ __launch_bounds__(256) void k_cvt(const float* __restrict__ x,
                                             unsigned short* __restrict__ xb) {
    size_t i = ((size_t)blockIdx.x * 256 + threadIdx.x) * 8;
    fl4 a = *(const fl4*)(x + i);
    fl4 b = *(const fl4*)(x + i + 4);
    us8 r;
    r[0] = f2bf(a[0]); r[1] = f2bf(a[1]); r[2] = f2bf(a[2]); r[3] = f2bf(a[3]);
    r[4] = f2bf(b[0]); r[5] = f2bf(b[1]); r[6] = f2bf(b[2]); r[7] = f2bf(b[3]);
    *(us8*)(xb + i) = r;
}

// ---------------------------------------------------------------------------
// k_prep: transpose+convert weights to bf16 [n][k]
__global__ void k_prep(const float* __restrict__ w_qkv, const float* __restrict__ w_out,
                       unsigned short* __restrict__ wqkvT, unsigned short* __restrict__ woutT) {
    int idx = blockIdx.x * 256 + threadIdx.x;
    if (idx < TRIPLE * DIM_) {
        int n = idx / DIM_, k = idx - n * DIM_;
        wqkvT[idx] = f2bf(w_qkv[(size_t)k * TRIPLE + n]);
    }
    if (idx < DIM_ * DIM_) {
        int n = idx / DIM_, k = idx - n * DIM_;
        woutT[idx] = f2bf(w_out[(size_t)k * DIM_ + n]);
    }
}

// ---------------------------------------------------------------------------
// k_qkv_a: m97-style async-staged GEMM.  C[65536x1536] = xb @ w_qkv.
// 128x128 tile, BK=32, unpadded LDS, global_load_lds width=16 for A and B.
__global__ __launch_bounds__(256) void k_qkv_a(const unsigned short* __restrict__ xb,
        const unsigned short* __restrict__ wT,      // [1536][512] bf16
        unsigned short* __restrict__ qkv)           // [65536][1536] bf16
{
    __shared__ unsigned short As[128 * 32];
    __shared__ unsigned short Bs[128 * 32];
    int t = threadIdx.x;
    int lane = t & 63, wave = t >> 6;
    int m0 = blockIdx.y * 128;
    int n0 = blockIdx.x * 128;
    int wm = (wave & 1) * 64, wn = (wave >> 1) * 64;
    int lr = lane & 15, kg = (lane >> 4) * 8;
    int srow = lane >> 2;            // 0..15 within 16-row stripe
    int scol = (lane & 3) * 8;       // ushort col offset (16B granule)

    f32x4 acc[4][4] = {};
    for (int k0 = 0; k0 < DIM_; k0 += 32) {
#pragma unroll
        for (int i = 0; i < 2; ++i) {
            int c = wave * 2 + i;    // 0..7 : stripe of 16 rows (1024B)
            int r = c * 16 + srow;
            gld16(xb + (size_t)(m0 + r) * DIM_ + k0 + scol, &As[c * 512]);
            gld16(wT + (size_t)(n0 + r) * DIM_ + k0 + scol, &Bs[c * 512]);
        }
        __syncthreads();             // drains vmcnt -> LDS tiles complete
        short8 af[4], bfr[4];
#pragma unroll
        for (int i = 0; i < 4; ++i) af[i]  = *(short8*)&As[(wm + i*16 + lr) * 32 + kg];
#pragma unroll
        for (int j = 0; j < 4; ++j) bfr[j] = *(short8*)&Bs[(wn + j*16 + lr) * 32 + kg];
#pragma unroll
        for (int i = 0; i < 4; ++i)
#pragma unroll
            for (int j = 0; j < 4; ++j)
                acc[i][j] = __builtin_amdgcn_mfma_f32_16x16x32_bf16(af[i], bfr[j], acc[i][j], 0, 0, 0);
        __syncthreads();
    }
#pragma unroll
    for (int i = 0; i < 4; ++i) {
        int row = m0 + wm + i*16 + (lane >> 4) * 4;
#pragma unroll
        for (int j = 0; j < 4; ++j) {
            int col = n0 + wn + j*16 + (lane & 15);
            bool rl = (col < 1024);
#pragma unroll
            for (int r = 0; r < 4; ++r) {
                float v = acc[i][j][r];
                if (rl && v < 0.0f) v = 0.0f;
                qkv[(size_t)(row + r) * TRIPLE + col] = f2bf(v);
            }
        }
    }
}

// ---------------------------------------------------------------------------
// k_qkv_f: fallback (round-1 kernel) if ws too small for bf16 x copy.
__global__ __launch_bounds__(256) void k_qkv_f(const float* __restrict__ x,
        const unsigned short* __restrict__ wT,
        unsigned short* __restrict__ qkv)
{
    __shared__ unsigned short As[128][40];
    __shared__ unsigned short Bs[128][40];
    int t = threadIdx.x;
    int lane = t & 63, wave = t >> 6;
    int m0 = blockIdx.y * 128;
    int n0 = blockIdx.x * 128;
    int wm = (wave & 1) * 64, wn = (wave >> 1) * 64;
    int lr = lane & 15, kg = (lane >> 4) * 8;

    f32x4 acc[4][4] = {};
    for (int k0 = 0; k0 < DIM_; k0 += 32) {
#pragma unroll
        for (int i = 0; i < 4; ++i) {
            int c = t + 256 * i;
            int r = c >> 3, c4 = (c & 7) * 4;
            fl4 v = *(const fl4*)(x + (size_t)(m0 + r) * DIM_ + k0 + c4);
            unsigned short* dst = &As[r][c4];
            dst[0] = f2bf(v[0]); dst[1] = f2bf(v[1]); dst[2] = f2bf(v[2]); dst[3] = f2bf(v[3]);
        }
#pragma unroll
        for (int i = 0; i < 2; ++i) {
            int c = t + 256 * i;
            int r = c >> 2, c8 = (c & 3) * 8;
            *(int4*)&Bs[r][c8] = *(const int4*)(wT + (size_t)(n0 + r) * DIM_ + k0 + c8);
        }
        __syncthreads();
        short8 af[4], bfr[4];
#pragma unroll
        for (int i = 0; i < 4; ++i) af[i]  = *(short8*)&As[wm + i*16 + lr][kg];
#pragma unroll
        for (int j = 0; j < 4; ++j) bfr[j] = *(short8*)&Bs[wn + j*16 + lr][kg];
#pragma unroll
        for (int i = 0; i < 4; ++i)
#pragma unroll
            for (int j = 0; j < 4; ++j)
                acc[i][j] = __builtin_amdgcn_mfma_f32_16x16x32_bf16(af[i], bfr[j], acc[i][j], 0, 0, 0);
        __syncthreads();
    }
#pragma unroll
    for (int i = 0; i < 4; ++i) {
        int row = m0 + wm + i*16 + (lane >> 4) * 4;
#pragma unroll
        for (int j = 0; j < 4; ++j) {
            int col = n0 + wn + j*16 + (lane & 15);
            bool rl = (col < 1024);
#pragma unroll
            for (int r = 0; r < 4; ++r) {
                float v = acc[i][j][r];
                if (rl && v < 0.0f) v = 0.0f;
                qkv[(size_t)(row + r) * TRIPLE + col] = f2bf(v);
            }
        }
    }
}

// ---------------------------------------------------------------------------
// k_kv: kv[b,h] (64x64) = sum_n relu(k)[n][m] * v[n][d].
__global__ __launch_bounds__(256) void k_kv(const unsigned short* __restrict__ qkv,
                                            float* __restrict__ kv) // [64][64][64] fp32
{
    __shared__ unsigned short KT[64][136];
    __shared__ unsigned short VT[64][136];
    __shared__ float red[64 * 64];
    int t = threadIdx.x, lane = t & 63, wave = t >> 6;
    int bh = blockIdx.x;
    int b = bh >> 3, h = bh & 7;
    int chunk = blockIdx.y;
    size_t rowbase = (size_t)b * N_ + (size_t)chunk * 1024;
    int kcol = DIM_ + h * 64;
    int vcol = 2 * DIM_ + h * 64;
    int lr = lane & 15;

    f32x4 acc[4][4] = {};
    for (int tile = 0; tile < 8; ++tile) {
        size_t r0 = rowbase + tile * 128;
#pragma unroll
        for (int i = 0; i < 8; ++i) {
            int c = t + 256 * i;
            int r = c >> 4, f4 = (c & 15) * 4;
            us4 kq = *(const us4*)(qkv + (r0 + r) * TRIPLE + kcol + f4);
            us4 vq = *(const us4*)(qkv + (r0 + r) * TRIPLE + vcol + f4);
#pragma unroll
            for (int j = 0; j < 4; ++j) { KT[f4 + j][r] = kq[j]; VT[f4 + j][r] = vq[j]; }
        }
        __syncthreads();
        int kg = wave * 32 + (lane >> 4) * 8;
        short8 af[4], bfr[4];
#pragma unroll
        for (int i = 0; i < 4; ++i) af[i]  = *(short8*)&KT[i*16 + lr][kg];
#pragma unroll
        for (int j = 0; j < 4; ++j) bfr[j] = *(short8*)&VT[j*16 + lr][kg];
#pragma unroll
        for (int i = 0; i < 4; ++i)
#pragma unroll
            for (int j = 0; j < 4; ++j)
                acc[i][j] = __builtin_amdgcn_mfma_f32_16x16x32_bf16(af[i], bfr[j], acc[i][j], 0, 0, 0);
        __syncthreads();
    }
    for (int w = 0; w < 4; ++w) {
        if (wave == w) {
#pragma unroll
            for (int i = 0; i < 4; ++i)
#pragma unroll
                for (int j = 0; j < 4; ++j)
#pragma unroll
                    for (int r = 0; r < 4; ++r) {
                        int m = i*16 + (lane >> 4) * 4 + r;
                        int d = j*16 + (lane & 15);
                        if (w == 0) red[m * 64 + d] = acc[i][j][r];
                        else        red[m * 64 + d] += acc[i][j][r];
                    }
        }
        __syncthreads();
    }
    float* kvout = kv + (size_t)bh * 4096;
#pragma unroll
    for (int i = 0; i < 16; ++i) {
        int idx = t + 256 * i;
        atomicAdd(&kvout[idx], red[idx]);
    }
}

// ---------------------------------------------------------------------------
// k_attn: attn = relu(q) @ kv per head (K=64), written in place over Q cols.
__global__ __launch_bounds__(256) void k_attn(unsigned short* __restrict__ qkv,
                                              const float* __restrict__ kv)
{
    __shared__ unsigned short Qh[128][72];
    __shared__ unsigned short kvT[64][72];
    int t = threadIdx.x, lane = t & 63, wave = t >> 6;
    size_t r0 = (size_t)blockIdx.x * 128;
    int b = (int)(r0 / N_);
    int lr = lane & 15;
    for (int h = 0; h < H_; ++h) {
#pragma unroll
        for (int i = 0; i < 8; ++i) {
            int c = t + 256 * i;
            int r = c >> 4, f4 = (c & 15) * 4;
            *(us4*)&Qh[r][f4] = *(const us4*)(qkv + (r0 + r) * TRIPLE + h * 64 + f4);
        }
        const float* kvh = kv + (size_t)(b * 8 + h) * 4096;
#pragma unroll
        for (int i = 0; i < 16; ++i) {
            int idx = t + 256 * i;
            int m = idx >> 6, d = idx & 63;
            kvT[d][m] = f2bf(kvh[idx]);
        }
        __syncthreads();
        f32x4 acc[2][4] = {};
#pragma unroll
        for (int ks = 0; ks < 2; ++ks) {
            int kg = ks * 32 + (lane >> 4) * 8;
            short8 af[2], bfr[4];
#pragma unroll
            for (int i = 0; i < 2; ++i) af[i]  = *(short8*)&Qh[wave*32 + i*16 + lr][kg];
#pragma unroll
            for (int j = 0; j < 4; ++j) bfr[j] = *(short8*)&kvT[j*16 + lr][kg];
#pragma unroll
            for (int i = 0; i < 2; ++i)
#pragma unroll
                for (int j = 0; j < 4; ++j)
                    acc[i][j] = __builtin_amdgcn_mfma_f32_16x16x32_bf16(af[i], bfr[j], acc[i][j], 0, 0, 0);
        }
        __syncthreads();
#pragma unroll
        for (int i = 0; i < 2; ++i)
#pragma unroll
            for (int j = 0; j < 4; ++j) {
                int row = wave*32 + i*16 + (lane >> 4) * 4;
                int col = h*64 + j*16 + (lane & 15);
#pragma unroll
                for (int r = 0; r < 4; ++r)
                    qkv[(r0 + row + r) * TRIPLE + col] = f2bf(acc[i][j][r]);
            }
    }
}

// ---------------------------------------------------------------------------
// k_out: LayerNorm(attn) @ w_out + b_out -> fp32 out.
__global__ __launch_bounds__(256) void k_out(const unsigned short* __restrict__ qkv,
        const unsigned short* __restrict__ woutT,
        const float* __restrict__ lnw, const float* __restrict__ lnb,
        const float* __restrict__ bout, float* __restrict__ out)
{
    __shared__ unsigned short As[128][40];
    __shared__ unsigned short Bs[128][40];
    __shared__ float mu[128], rs[128], lw[512], lb[512];
    int t = threadIdx.x, lane = t & 63, wave = t >> 6;
    int m0 = blockIdx.y * 128, n0 = blockIdx.x * 128;
    int wm = (wave & 1) * 64, wn = (wave >> 1) * 64;
    int lr = lane & 15, kg = (lane >> 4) * 8;

    for (int i = t; i < 512; i += 256) { lw[i] = lnw[i]; lb[i] = lnb[i]; }
    {
        int row = t >> 1, half = t & 1;
        const unsigned short* p = qkv + (size_t)(m0 + row) * TRIPLE + half * 256;
        float s = 0.0f, ss = 0.0f;
#pragma unroll 8
        for (int i = 0; i < 64; ++i) {
            us4 v = *(const us4*)(p + i * 4);
#pragma unroll
            for (int j = 0; j < 4; ++j) { float f = bf2f(v[j]); s += f; ss += f * f; }
        }
        s  += __shfl_xor(s, 1);
        ss += __shfl_xor(ss, 1);
        if (half == 0) {
            float m = s * (1.0f / 512.0f);
            float var = ss * (1.0f / 512.0f) - m * m;
            mu[row] = m;
            rs[row] = rsqrtf(var + EPS_);
        }
    }
    __syncthreads();

    f32x4 acc[4][4] = {};
    for (int k0 = 0; k0 < 512; k0 += 32) {
#pragma unroll
        for (int i = 0; i < 4; ++i) {
            int c = t + 256 * i;
            int r = c >> 3, c4 = (c & 7) * 4;
            us4 v = *(const us4*)(qkv + (size_t)(m0 + r) * TRIPLE + k0 + c4);
            float mm = mu[r], rr = rs[r];
            unsigned short* dst = &As[r][c4];
#pragma unroll
            for (int j = 0; j < 4; ++j) {
                float f = (bf2f(v[j]) - mm) * rr * lw[k0 + c4 + j] + lb[k0 + c4 + j];
                dst[j] = f2bf(f);
            }
        }
#pragma unroll
        for (int i = 0; i < 2; ++i) {
            int c = t + 256 * i;
            int r = c >> 2, c8 = (c & 3) * 8;
            *(int4*)&Bs[r][c8] = *(const int4*)(woutT + (size_t)(n0 + r) * DIM_ + k0 + c8);
        }
        __syncthreads();
        short8 af[4], bfr[4];
#pragma unroll
        for (int i = 0; i < 4; ++i) af[i]  = *(short8*)&As[wm + i*16 + lr][kg];
#pragma unroll
        for (int j = 0; j < 4; ++j) bfr[j] = *(short8*)&Bs[wn + j*16 + lr][kg];
#pragma unroll
        for (int i = 0; i < 4; ++i)
#pragma unroll
            for (int j = 0; j < 4; ++j)
                acc[i][j] = __builtin_amdgcn_mfma_f32_16x16x32_bf16(af[i], bfr[j], acc[i][j], 0, 0, 0);
        __syncthreads();
    }
#pragma unroll
    for (int i = 0; i < 4; ++i) {
        int row = m0 + wm + i*16 + (lane >> 4) * 4;
#pragma unroll
        for (int j = 0; j < 4; ++j) {
            int col = n0 + wn + j*16 + (lane & 15);
            float bo = bout[col];
#pragma unroll
            for (int r = 0; r < 4; ++r)
                out[(size_t)(row + r) * DIM_ + col] = acc[i][j][r] + bo;
        }
    }
}

// ---------------------------------------------------------------------------
extern "C" void kernel_launch(void* const* d_in, const int* in_sizes, int n_in,
                              void* d_out, int out_size, void* d_ws, size_t ws_size,
                              hipStream_t stream) {
    (void)in_sizes; (void)n_in; (void)out_size;
    const float* x     = (const float*)d_in[0];
    const float* w_qkv = (const float*)d_in[1];
    const float* ln_w  = (const float*)d_in[2];
    const float* ln_b  = (const float*)d_in[3];
    const float* w_out = (const float*)d_in[4];
    const float* b_out = (const float*)d_in[5];
    float* out = (float*)d_out;

    char* ws = (char*)d_ws;
    const size_t QKV_BYTES = (size_t)ROWS * TRIPLE * sizeof(unsigned short); // 201326592
    const size_t KV_BYTES  = (size_t)64 * 64 * 64 * sizeof(float);           // 1048576
    const size_t WQT_BYTES = (size_t)TRIPLE * DIM_ * sizeof(unsigned short); // 1572864
    const size_t WOT_BYTES = (size_t)DIM_ * DIM_ * sizeof(unsigned short);   // 524288
    const size_t XB_BYTES  = (size_t)ROWS * DIM_ * sizeof(unsigned short);   // 67108864
    unsigned short* qkv   = (unsigned short*)ws;
    float*          kvbuf = (float*)(ws + QKV_BYTES);
    unsigned short* wqkvT = (unsigned short*)(ws + QKV_BYTES + KV_BYTES);
    unsigned short* woutT = (unsigned short*)(ws + QKV_BYTES + KV_BYTES + WQT_BYTES);
    unsigned short* xb    = (unsigned short*)(ws + QKV_BYTES + KV_BYTES + WQT_BYTES + WOT_BYTES);
    const size_t NEED = QKV_BYTES + KV_BYTES + WQT_BYTES + WOT_BYTES + XB_BYTES;

    hipMemsetAsync(kvbuf, 0, KV_BYTES, stream);
    k_prep<<<3072, 256, 0, stream>>>(w_qkv, w_out, wqkvT, woutT);
    if (ws_size >= NEED) {
        k_cvt<<<16384, 256, 0, stream>>>(x, xb);
        k_qkv_a<<<dim3(12, 512), 256, 0, stream>>>(xb, wqkvT, qkv);
    } else {
        k_qkv_f<<<dim3(12, 512), 256, 0, stream>>>(x, wqkvT, qkv);
    }
    k_kv<<<dim3(64, 8), 256, 0, stream>>>(qkv, kvbuf);
    k_attn<<<512, 256, 0, stream>>>(qkv, kvbuf);
    k_out<<<dim3(4, 512), 256, 0, stream>>>(qkv, woutT, ln_w, ln_b, b_out, out);
}